// Round 16
// baseline (27.953 us; speedup 1.0000x reference)
//
#include <hip/hip_runtime.h>
#include <math.h>

// y_t = clamp(y_{t-1}, x_t, x_t+1): play operator as associative clamp-scan.
// compose(l, r) = "apply l first, then r". min/max/med3-only => exact =>
// any regrouping is bit-identical (deterministic).
//
// COLLAPSE PROPERTY: composed windows contract and width-0 is absorbing.
// Element 0's window is (p0,p0), so ANY prefix reaching element 0 is
// collapsed. Each block recomputes its exact incoming value from the RAW
// INPUT halo (backward 256-element chunks until collapse; guaranteed at
// element 0). NO inter-block communication (rounds 2/10/11: cross-XCD sync
// through non-coherent L2s costs 2-6x, fenced or relaxed).
//
// GROUPS LAYOUT (round 15 lesson: LDS transpose was never the limiter; the
// strided 64B-lane-stride loads were): tile = 4 groups x 1024; in group v,
// thread t owns elements tile0+1024v+4t..+3 -- one float4, lane-contiguous.
// Loads AND stores are 1 KB/wave/instruction (fill-kernel pattern); no LDS
// transpose. Scan: per-group wave scans (1 barrier), halo walk, then value-
// chain through group aggregates.

#define TPB 256
#define GPB 4                 // groups per block
#define GSZ (TPB * 4)         // 1024 elements per group
#define EPB (GPB * GSZ)       // 4096 per block -> nb = 4097 for T=2^24
#define NW  (TPB / 64)
#define HCH 256               // halo chunk: 1 element per thread

struct Pair { float a, b; };

__device__ __forceinline__ float med3f(float x, float lo, float hi) {
    return __builtin_amdgcn_fmed3f(x, lo, hi);   // clamp(x, lo, hi), lo<=hi
}
__device__ __forceinline__ Pair compose(Pair l, Pair r) {
    Pair o; o.a = med3f(l.a, r.a, r.b); o.b = med3f(l.b, r.a, r.b); return o;
}
__device__ __forceinline__ Pair ident() {
    Pair p; p.a = -INFINITY; p.b = INFINITY; return p;
}

__global__ __launch_bounds__(TPB)
void k_scan(const float* __restrict__ in, const float* __restrict__ kptr,
            float* __restrict__ out, int n) {
    const int tid  = threadIdx.x, lane = tid & 63, wid = tid >> 6;
    const int vid  = blockIdx.x;
    const int tile0 = vid * EPB;
    const float k   = kptr[0];
    const bool blockFull = (tile0 + EPB <= n);   // uniform across block

    __shared__ Pair wS[GPB][NW];   // per-group wave aggregates (128 B)
    __shared__ Pair wC[NW];        // halo-chunk wave aggregates

    // ---- 0) prefetch first halo chunk (latency hides under tile phase) ----
    float hx = 0.0f;
    if (tile0 > 0) hx = in[tile0 - HCH + tid];

    // ---- 1) per-group: lane-contiguous load, thread windows, wave scan ----
    float ta[GPB][4], tb[GPB][4];                // static indexing only
    Pair  upv[GPB];                              // shfl_up(w,1) per group
    #pragma unroll
    for (int v = 0; v < GPB; ++v) {
        const int b4 = tile0 + v * GSZ + 4 * tid;
        float xv[4];
        if (blockFull) {
            float4 f = reinterpret_cast<const float4*>(in + tile0 + v * GSZ)[tid];
            xv[0] = f.x; xv[1] = f.y; xv[2] = f.z; xv[3] = f.w;
        } else {
            #pragma unroll
            for (int j = 0; j < 4; ++j)
                xv[j] = (b4 + j < n) ? in[b4 + j] : 0.0f;
        }
        float a = -INFINITY, b = INFINITY;
        #pragma unroll
        for (int j = 0; j < 4; ++j) {
            if (blockFull || b4 + j < n) {
                float lo = xv[j] * k, hi = lo + 1.0f;
                if (j == 0 && b4 == 0) { lo = xv[0]; hi = xv[0]; }  // const p0
                a = med3f(a, lo, hi);
                b = med3f(b, lo, hi);
            }
            ta[v][j] = a; tb[v][j] = b;
        }
        Pair w; w.a = a; w.b = b;
        #pragma unroll
        for (int off = 1; off < 64; off <<= 1) {
            Pair u; u.a = __shfl_up(w.a, off); u.b = __shfl_up(w.b, off);
            if (lane >= off) w = compose(u, w);
        }
        upv[v].a = __shfl_up(w.a, 1); upv[v].b = __shfl_up(w.b, 1);
        if (lane == 63) wS[v][wid] = w;
    }
    __syncthreads();                             // one barrier for all scans

    // ---- 2) halo backward walk: exact incoming value, no communication ----
    Pair S = ident();
    int chunkEnd = tile0;
    bool first = true;
    while (chunkEnd > 0) {
        const int chunkStart = chunkEnd - HCH;   // tile0 % HCH == 0
        const int e = chunkStart + tid;
        float x = first ? hx : in[e];
        first = false;
        Pair wnd;
        {
            float lo = x * k, hi = lo + 1.0f;
            if (e == 0) { lo = x; hi = x; }      // constant p0
            wnd.a = lo; wnd.b = hi;
        }
        // ordered wave tree-reduce; lane 0 = ascending-order wave aggregate
        #pragma unroll
        for (int off = 1; off < 64; off <<= 1) {
            Pair u; u.a = __shfl_down(wnd.a, off); u.b = __shfl_down(wnd.b, off);
            Pair c = compose(wnd, u);
            if (lane + off < 64) wnd = c;
        }
        if (lane == 0) wC[wid] = wnd;
        __syncthreads();
        Pair cagg = wC[0];
        #pragma unroll
        for (int i = 1; i < NW; ++i) cagg = compose(cagg, wC[i]);
        __syncthreads();                         // protect wC for next iter
        S = compose(cagg, S);                    // prepend older chunk
        if (S.a == S.b) break;                   // collapsed: exact
        chunkEnd = chunkStart;
    }
    float y = med3f(0.0f, S.a, S.b);             // vid 0: med3(0,-inf,inf)=0

    // ---- 3) per-group apply + chain: lane-contiguous float4 stores --------
    #pragma unroll
    for (int v = 0; v < GPB; ++v) {
        Pair wpre = ident();
        #pragma unroll
        for (int i = 0; i < NW; ++i) if (i < wid) wpre = compose(wpre, wS[v][i]);
        Pair ex = (lane == 0) ? wpre : compose(wpre, upv[v]);
        const float ytin = med3f(y, ex.a, ex.b); // exact incoming value
        // chain y across groups via the group aggregate
        Pair G = wS[v][0];
        #pragma unroll
        for (int i = 1; i < NW; ++i) G = compose(G, wS[v][i]);
        y = med3f(y, G.a, G.b);

        const int b4 = tile0 + v * GSZ + 4 * tid;
        if (blockFull) {
            float4 o;
            o.x = med3f(ytin, ta[v][0], tb[v][0]);
            o.y = med3f(ytin, ta[v][1], tb[v][1]);
            o.z = med3f(ytin, ta[v][2], tb[v][2]);
            o.w = med3f(ytin, ta[v][3], tb[v][3]);
            reinterpret_cast<float4*>(out + tile0 + v * GSZ)[tid] = o;
        } else {
            #pragma unroll
            for (int j = 0; j < 4; ++j)
                if (b4 + j < n) out[b4 + j] = med3f(ytin, ta[v][j], tb[v][j]);
        }
    }
}

// ========================== host launcher ==================================
extern "C" void kernel_launch(void* const* d_in, const int* in_sizes, int n_in,
                              void* d_out, int out_size, void* d_ws, size_t ws_size,
                              hipStream_t stream) {
    const float* in   = (const float*)d_in[0];   // [T+1], in[0] = p0
    const float* kptr = (const float*)d_in[1];   // scalar weight
    float* out = (float*)d_out;                  // [T+1]
    const int n  = in_sizes[0];
    const int nb = (n + EPB - 1) / EPB;          // 4097 for T = 2^24

    k_scan<<<nb, TPB, 0, stream>>>(in, kptr, out, n);
}